// Round 2
// baseline (238.648 us; speedup 1.0000x reference)
//
#include <hip/hip_runtime.h>
#include <stdint.h>

#define AS1 __attribute__((address_space(1)))
#define AS3 __attribute__((address_space(3)))

typedef float   f32x2  __attribute__((ext_vector_type(2)));
typedef float   f32x4  __attribute__((ext_vector_type(4)));
typedef __bf16  bf16x8 __attribute__((ext_vector_type(8)));
typedef uint32_t u32x4 __attribute__((ext_vector_type(4)));

// Round-half-up fp32->bf16 for a pair, packed into one dword: low16 = lo, high16 = hi.
__device__ __forceinline__ uint32_t pack_rnd(float lo, float hi) {
    uint32_t a = __float_as_uint(hi) + 0x8000u;
    uint32_t b = __float_as_uint(lo) + 0x8000u;
    return __builtin_amdgcn_perm(a, b, 0x07060302u); // bytes: a3 a2 b3 b2
}

// ---------------- Pre-kernel: weight [512][1024] fp32 -> Wt [1024][512] bf16 --------------
__global__ __launch_bounds__(256) void wt_prep(const float* __restrict__ w,
                                               uint16_t* __restrict__ wt) {
    int t = blockIdx.x * 256 + threadIdx.x;   // 131072 threads
    int n = t & 1023;
    int c = (t >> 10) << 2;                   // c-quad base, 0..508
    const float* p = w + (size_t)c * 1024 + n;
    float f0 = p[0], f1 = p[1024], f2 = p[2048], f3 = p[3072];
    uint2 r;
    r.x = pack_rnd(f0, f1);
    r.y = pack_rnd(f2, f3);
    *(uint2*)(wt + (size_t)n * 512 + c) = r;
}

// ---------------- Main kernel: D[n][m] = Wt · X, fused bias + pixel-shuffle epilogue ------
// BM=128 (pixels), BN=128, BK=32, 256 threads (4 waves), wave = 64x64 subtile.
// v3: v1's proven 2-barrier dataflow, but BK=32 -> LDS 26.6 KB -> 6 blocks/CU (24 waves).
//     Latency-bound regime: double the TLP instead of deepening the per-wave pipeline.
__global__ __launch_bounds__(256) void tconv_gemm(const float* __restrict__ x,
                                                  const uint16_t* __restrict__ wt,
                                                  const float* __restrict__ bias,
                                                  float* __restrict__ out) {
    // LDS: W dbuf [2][128][32] bf16 @ 0 (4096 elems each), X [128][40] @ 8192 (pad 8 elems:
    // 80 B row stride spreads read banks; X is reg-staged so padding is legal).
    __shared__ uint16_t lds[13312]; // 26.62 KB -> 6 blocks/CU

    const int tid  = threadIdx.x;
    const int l    = tid & 63;
    const int wv   = tid >> 6;
    const int l15  = l & 15;
    const int quad = l >> 4;

    // XCD-aware decode: 8 consecutive blocks on one XCD share the same X tile (L2 reuse).
    const int bid  = blockIdx.x;
    const int xcd  = bid & 7;
    const int jj   = bid >> 3;
    const int nblk = jj & 7;                 // 0..7   (n-tile)
    const int mblk = xcd * 32 + (jj >> 3);   // 0..255 (m-tile)

    const int b  = mblk >> 5;                // batch
    const int p0 = (mblk & 31) * 128;        // pixel offset in batch
    const int n0 = nblk * 128;

    const float* xblk = x + ((size_t)b * 512) * 4096 + p0;

    // ---- X staging: wave wv owns k-octet (k = kt*32 + wv*8 + r), lanes cover m in pairs ----
    const int m2 = l * 2;
    const float* xsrc = xblk + (size_t)wv * 8 * 4096 + m2;
    int xw_off[2];
#pragma unroll
    for (int mm = 0; mm < 2; ++mm) {
        int m = m2 + mm;
        xw_off[mm] = 8192 + m * 40 + ((wv ^ ((m >> 1) & 3)) << 3);
    }

    // ---- W gll: lane covers (row rr, chunk cc); swizzle applied to GLOBAL addr ----
    const int rr = l >> 2, cc = l & 3;       // 16 rows x 4 chunks (32 k = 4 chunks of 8)
    int wg_off[2], wl_off[2];
#pragma unroll
    for (int i = 0; i < 2; ++i) {
        int n_r  = wv * 32 + i * 16 + rr;
        int cs   = cc ^ ((n_r >> 1) & 3);
        wg_off[i] = (n0 + n_r) * 512 + cs * 8;   // elements; + kt*32 per iter
        wl_off[i] = (wv * 32 + i * 16) * 32;     // wave-uniform LDS base (buffer-relative)
    }

    // ---- fragment read offsets (swizzled) ----
    const int wave_n = (wv >> 1) * 64;
    const int wave_m = (wv & 1) * 64;
    int a_off[4], b_off[4];
#pragma unroll
    for (int t2 = 0; t2 < 4; ++t2) {
        int n = wave_n + t2 * 16 + l15;
        a_off[t2] = n * 32 + ((quad ^ ((n >> 1) & 3)) << 3);
        int m = wave_m + t2 * 16 + l15;
        b_off[t2] = 8192 + m * 40 + ((quad ^ ((m >> 1) & 3)) << 3);
    }

    f32x4 acc[4][4];
#pragma unroll
    for (int a = 0; a < 4; ++a)
#pragma unroll
        for (int c = 0; c < 4; ++c) acc[a][c] = f32x4{0.f, 0.f, 0.f, 0.f};

    // ---- prologue: W(0) gll -> buf0; X(0) -> regs ----
#pragma unroll
    for (int i = 0; i < 2; ++i)
        __builtin_amdgcn_global_load_lds((AS1 void*)(wt + wg_off[i]),
                                         (AS3 void*)(lds + wl_off[i]), 16, 0, 0);
    f32x2 v[8];
#pragma unroll
    for (int r = 0; r < 8; ++r) v[r] = *(const f32x2*)(xsrc + (size_t)r * 4096);

    for (int kt = 0; kt < 16; ++kt) {
        // stage X(kt): convert + swizzled b128 writes (buffer freed by barrier B of kt-1)
#pragma unroll
        for (int mm = 0; mm < 2; ++mm) {
            u32x4 pk;
            pk.x = pack_rnd(v[0][mm], v[1][mm]);
            pk.y = pack_rnd(v[2][mm], v[3][mm]);
            pk.z = pack_rnd(v[4][mm], v[5][mm]);
            pk.w = pack_rnd(v[6][mm], v[7][mm]);
            *(u32x4*)(lds + xw_off[mm]) = pk;
        }
        __syncthreads(); // A: X(kt) visible; W(kt) was drained by barrier B of kt-1

        const int cur = (kt & 1) * 4096;
        if (kt < 15) {
            // issue next W gll + X global loads NOW -> overlap the 16 MFMAs,
            // drained for free by the end-of-iteration barrier.
            const int nxt = ((kt + 1) & 1) * 4096;
            const uint16_t* wg = wt + (kt + 1) * 32;
#pragma unroll
            for (int i = 0; i < 2; ++i)
                __builtin_amdgcn_global_load_lds((AS1 void*)(wg + wg_off[i]),
                                                 (AS3 void*)(lds + nxt + wl_off[i]), 16, 0, 0);
            const float* xs = xsrc + (size_t)(kt + 1) * 32 * 4096;
#pragma unroll
            for (int r = 0; r < 8; ++r) v[r] = *(const f32x2*)(xs + (size_t)r * 4096);
        }

        // compute kt: 4 A-frags + 4 B-frags + 16 MFMAs
        bf16x8 af[4], bf[4];
#pragma unroll
        for (int t2 = 0; t2 < 4; ++t2) af[t2] = *(const bf16x8*)(lds + cur + a_off[t2]);
#pragma unroll
        for (int t2 = 0; t2 < 4; ++t2) bf[t2] = *(const bf16x8*)(lds + b_off[t2]);
#pragma unroll
        for (int tn = 0; tn < 4; ++tn)
#pragma unroll
            for (int tm = 0; tm < 4; ++tm)
                acc[tn][tm] = __builtin_amdgcn_mfma_f32_16x16x32_bf16(
                    af[tn], bf[tm], acc[tn][tm], 0, 0, 0);

        __syncthreads(); // B: X buffer reusable; drains this iter's prefetches (needed anyway)
    }

    // ---- epilogue: regs 0..3 = one o's (i,j) 2x2 block; lanes 0..15 = consecutive w ----
    const int o_base = nblk * 32 + (wave_n >> 2) + quad;
    const int y_base = (mblk & 31) * 4;
    float* outb = out + (size_t)b * 256 * 16384;
#pragma unroll
    for (int tn = 0; tn < 4; ++tn) {
        int o = o_base + tn * 4;
        float bv = bias[o];
#pragma unroll
        for (int tm = 0; tm < 4; ++tm) {
            int loc = wave_m + tm * 16 + l15;
            int hl  = loc >> 6;
            int ww  = loc & 63;
            float* p = outb + ((size_t)o * 128 + (y_base + 2 * hl)) * 128 + 2 * ww;
            f32x4 a = acc[tn][tm];
            float2 t0; t0.x = a.x + bv; t0.y = a.y + bv;   // (i=0, j=0,1)
            float2 t1; t1.x = a.z + bv; t1.y = a.w + bv;   // (i=1, j=0,1)
            *(float2*)(p)       = t0;
            *(float2*)(p + 128) = t1;
        }
    }
}

extern "C" void kernel_launch(void* const* d_in, const int* in_sizes, int n_in,
                              void* d_out, int out_size, void* d_ws, size_t ws_size,
                              hipStream_t stream) {
    const float* x    = (const float*)d_in[0];  // [8][512][64][64]
    const float* w    = (const float*)d_in[1];  // [512][256][2][2] = [512][1024]
    const float* bias = (const float*)d_in[2];  // [256]
    float* out        = (float*)d_out;          // [8][256][128][128]
    uint16_t* wt      = (uint16_t*)d_ws;        // [1024][512] bf16 (1 MiB)

    wt_prep<<<512, 256, 0, stream>>>(w, wt);
    tconv_gemm<<<2048, 256, 0, stream>>>(x, wt, bias, out);
}

// Round 3
// 223.785 us; speedup vs baseline: 1.0664x; 1.0664x over previous
//
#include <hip/hip_runtime.h>
#include <stdint.h>

#define AS1 __attribute__((address_space(1)))
#define AS3 __attribute__((address_space(3)))

typedef float   f32x4  __attribute__((ext_vector_type(4)));
typedef __bf16  bf16x8 __attribute__((ext_vector_type(8)));
typedef uint32_t u32x4 __attribute__((ext_vector_type(4)));

// Round-half-up fp32->bf16 for a pair, packed into one dword: low16 = lo, high16 = hi.
__device__ __forceinline__ uint32_t pack_rnd(float lo, float hi) {
    uint32_t a = __float_as_uint(hi) + 0x8000u;
    uint32_t b = __float_as_uint(lo) + 0x8000u;
    return __builtin_amdgcn_perm(a, b, 0x07060302u); // bytes: a3 a2 b3 b2
}

// ---------------- Pre-kernel: weight [512][1024] fp32 -> Wt [1024][512] bf16 --------------
__global__ __launch_bounds__(256) void wt_prep(const float* __restrict__ w,
                                               uint16_t* __restrict__ wt) {
    int t = blockIdx.x * 256 + threadIdx.x;   // 131072 threads
    int n = t & 1023;
    int c = (t >> 10) << 2;                   // c-quad base, 0..508
    const float* p = w + (size_t)c * 1024 + n;
    float f0 = p[0], f1 = p[1024], f2 = p[2048], f3 = p[3072];
    uint2 r;
    r.x = pack_rnd(f0, f1);
    r.y = pack_rnd(f2, f3);
    *(uint2*)(wt + (size_t)n * 512 + c) = r;
}

// ---------------- Main kernel: D[n][m] = Wt · X, fused bias + pixel-shuffle epilogue ------
// BM=128 (pixels), BN=128, BK=64, 256 threads (4 waves), wave = 64x64 subtile.
// v4 = v1 geometry (48 KB LDS, 3 blocks/CU) + counted-vmcnt raw barriers (never drain the
// X prefetch) + 2-deep X register prefetch (shadow > HBM latency). Loop fully unrolled so
// the double reg-buffer is statically indexed (no scratch).
__global__ __launch_bounds__(256) void tconv_gemm(const float* __restrict__ x,
                                                  const uint16_t* __restrict__ wt,
                                                  const float* __restrict__ bias,
                                                  float* __restrict__ out) {
    // LDS: W double-buffered [2][128][64] bf16 @ 0, X [128][64] bf16 @ 16384 (elements)
    __shared__ uint16_t lds[24576]; // 48 KB

    const int tid  = threadIdx.x;
    const int l    = tid & 63;
    const int wv   = tid >> 6;
    const int l15  = l & 15;
    const int quad = l >> 4;

    // XCD-aware decode: 8 consecutive blocks on one XCD share the same X tile (L2 reuse).
    const int bid  = blockIdx.x;
    const int xcd  = bid & 7;
    const int jj   = bid >> 3;
    const int nblk = jj & 7;                 // 0..7   (n-tile)
    const int mblk = xcd * 32 + (jj >> 3);   // 0..255 (m-tile)

    const int b  = mblk >> 5;                // batch
    const int p0 = (mblk & 31) * 128;        // pixel offset in batch
    const int n0 = nblk * 128;

    const float* xblk = x + ((size_t)b * 512) * 4096 + p0;

    // ---- X staging constants: thread handles 8k x 4m micro-tile ----
    const int mq4 = (tid & 31) * 4;          // m base
    const int ko  = tid >> 5;                // k-octet 0..7
    const float* xsrc = xblk + (size_t)ko * 8 * 4096 + mq4;
    int xw_off[4];
#pragma unroll
    for (int mm = 0; mm < 4; ++mm) {
        int m = mq4 + mm;
        xw_off[mm] = 16384 + m * 64 + ((ko ^ ((m >> 1) & 7)) << 3);
    }

    // ---- W gll constants: lane covers (row rr, chunk cc); swizzle applied to GLOBAL addr ----
    const int rr = l >> 3, cc = l & 7;
    int wg_off[4], wl_off[4];
#pragma unroll
    for (int i = 0; i < 4; ++i) {
        int n_r  = wv * 32 + i * 8 + rr;
        int cs   = cc ^ ((n_r >> 1) & 7);
        wg_off[i] = (n0 + n_r) * 512 + cs * 8;   // elements, k0 added per iter
        wl_off[i] = (wv * 32 + i * 8) * 64;      // wave-uniform LDS base (buffer-relative)
    }

    // ---- fragment read offsets (swizzled, precomputed) ----
    const int wave_n = (wv >> 1) * 64;
    const int wave_m = (wv & 1) * 64;
    int a_off[2][4], b_off[2][4];
#pragma unroll
    for (int ks = 0; ks < 2; ++ks) {
#pragma unroll
        for (int t2 = 0; t2 < 4; ++t2) {
            int n = wave_n + t2 * 16 + l15;
            a_off[ks][t2] = n * 64 + (((ks * 4 + quad) ^ ((n >> 1) & 7)) << 3);
            int m = wave_m + t2 * 16 + l15;
            b_off[ks][t2] = 16384 + m * 64 + (((ks * 4 + quad) ^ ((m >> 1) & 7)) << 3);
        }
    }

    f32x4 acc[4][4];
#pragma unroll
    for (int a = 0; a < 4; ++a)
#pragma unroll
        for (int c = 0; c < 4; ++c) acc[a][c] = f32x4{0.f, 0.f, 0.f, 0.f};

    // ---- prologue: W(0) gll (oldest in vm queue!), then X(0) -> v[0], X(1) -> v[1] ----
#pragma unroll
    for (int i = 0; i < 4; ++i)
        __builtin_amdgcn_global_load_lds((AS1 void*)(wt + wg_off[i]),
                                         (AS3 void*)(lds + wl_off[i]), 16, 0, 0);
    asm volatile("" ::: "memory");           // pin: W(0) older than X loads
    f32x4 v[2][8];
#pragma unroll
    for (int r = 0; r < 8; ++r) v[0][r] = *(const f32x4*)(xsrc + (size_t)r * 4096);
#pragma unroll
    for (int r = 0; r < 8; ++r) v[1][r] = *(const f32x4*)(xsrc + (size_t)(64 * 4096) + (size_t)r * 4096);
    asm volatile("" ::: "memory");

    // ---- main loop (fully unrolled; all buffer indices static) ----
    // Invariant at barrier A of kt: vm queue = [W(kt) x4 (oldest), X(kt+1) x8] -> vmcnt(8)
    // releases when W(kt) landed, X prefetch stays in flight. Barrier B: lgkm only.
#pragma unroll
    for (int kt = 0; kt < 8; ++kt) {
        const int cb  = kt & 1;
        const int cur = cb * 8192;

        // stage X(kt) from v[cb] (loaded 2 iters ago; compiler emits the precise vmcnt)
#pragma unroll
        for (int mm = 0; mm < 4; ++mm) {
            u32x4 pk;
            pk.x = pack_rnd(v[cb][0][mm], v[cb][1][mm]);
            pk.y = pack_rnd(v[cb][2][mm], v[cb][3][mm]);
            pk.z = pack_rnd(v[cb][4][mm], v[cb][5][mm]);
            pk.w = pack_rnd(v[cb][6][mm], v[cb][7][mm]);
            *(u32x4*)(lds + xw_off[mm]) = pk;
        }

        // barrier A: my ds_writes visible + W(kt) gll landed; X(kt+1) stays outstanding
        if (kt < 7) {
            asm volatile("s_waitcnt vmcnt(8) lgkmcnt(0)" ::: "memory");
        } else {
            asm volatile("s_waitcnt vmcnt(0) lgkmcnt(0)" ::: "memory"); // only W(7) left
        }
        __builtin_amdgcn_sched_barrier(0);
        __builtin_amdgcn_s_barrier();
        __builtin_amdgcn_sched_barrier(0);

        if (kt < 7) {
            // issue W(kt+1) gll -> other W buffer (free: its reads finished last iter)
            const uint16_t* wg = wt + (kt + 1) * 64;
            const int nxt = (cb ^ 1) * 8192;
#pragma unroll
            for (int i = 0; i < 4; ++i)
                __builtin_amdgcn_global_load_lds((AS1 void*)(wg + wg_off[i]),
                                                 (AS3 void*)(lds + nxt + wl_off[i]), 16, 0, 0);
            asm volatile("" ::: "memory");   // pin: W(kt+1) older than X(kt+2)
        }
        if (kt < 6) {
            // issue X(kt+2) -> v[cb] (just consumed); consumed at iter kt+2 -> ~full-iter shadow
            const float* xs = xsrc + (size_t)(kt + 2) * 64 * 4096;
#pragma unroll
            for (int r = 0; r < 8; ++r) v[cb][r] = *(const f32x4*)(xs + (size_t)r * 4096);
            asm volatile("" ::: "memory");
        }

        // compute kt: 2 k-substeps x (4 A-frags + 4 B-frags + 16 MFMAs)
#pragma unroll
        for (int ks = 0; ks < 2; ++ks) {
            bf16x8 af[4], bf[4];
#pragma unroll
            for (int t2 = 0; t2 < 4; ++t2) af[t2] = *(const bf16x8*)(lds + cur + a_off[ks][t2]);
#pragma unroll
            for (int t2 = 0; t2 < 4; ++t2) bf[t2] = *(const bf16x8*)(lds + b_off[ks][t2]);
#pragma unroll
            for (int tn = 0; tn < 4; ++tn)
#pragma unroll
                for (int tm = 0; tm < 4; ++tm)
                    acc[tn][tm] = __builtin_amdgcn_mfma_f32_16x16x32_bf16(
                        af[tn], bf[tm], acc[tn][tm], 0, 0, 0);
        }

        // barrier B: X LDS reusable (ds_reads done). NO vmem drain -> prefetches survive.
        if (kt < 7) {
            asm volatile("s_waitcnt lgkmcnt(0)" ::: "memory");
            __builtin_amdgcn_sched_barrier(0);
            __builtin_amdgcn_s_barrier();
            __builtin_amdgcn_sched_barrier(0);
        }
    }

    // ---- epilogue: regs 0..3 = one o's (i,j) 2x2 block; lanes 0..15 = consecutive w ----
    const int o_base = nblk * 32 + (wave_n >> 2) + quad;
    const int y_base = (mblk & 31) * 4;
    float* outb = out + (size_t)b * 256 * 16384;
#pragma unroll
    for (int tn = 0; tn < 4; ++tn) {
        int o = o_base + tn * 4;
        float bv = bias[o];
#pragma unroll
        for (int tm = 0; tm < 4; ++tm) {
            int loc = wave_m + tm * 16 + l15;
            int hl  = loc >> 6;
            int ww  = loc & 63;
            float* p = outb + ((size_t)o * 128 + (y_base + 2 * hl)) * 128 + 2 * ww;
            f32x4 a = acc[tn][tm];
            float2 t0; t0.x = a.x + bv; t0.y = a.y + bv;   // (i=0, j=0,1)
            float2 t1; t1.x = a.z + bv; t1.y = a.w + bv;   // (i=1, j=0,1)
            *(float2*)(p)       = t0;
            *(float2*)(p + 128) = t1;
        }
    }
}

extern "C" void kernel_launch(void* const* d_in, const int* in_sizes, int n_in,
                              void* d_out, int out_size, void* d_ws, size_t ws_size,
                              hipStream_t stream) {
    const float* x    = (const float*)d_in[0];  // [8][512][64][64]
    const float* w    = (const float*)d_in[1];  // [512][256][2][2] = [512][1024]
    const float* bias = (const float*)d_in[2];  // [256]
    float* out        = (float*)d_out;          // [8][256][128][128]
    uint16_t* wt      = (uint16_t*)d_ws;        // [1024][512] bf16 (1 MiB)

    wt_prep<<<512, 256, 0, stream>>>(w, wt);
    tconv_gemm<<<2048, 256, 0, stream>>>(x, wt, bias, out);
}